// Round 19
// baseline (685.494 us; speedup 1.0000x reference)
//
#include <hip/hip_runtime.h>
#include <math.h>

typedef unsigned int u32;

// ---------- bf16 helpers ----------
__device__ __forceinline__ u32 pk2(float a, float b){
    u32 ua=__float_as_uint(a), ub=__float_as_uint(b);
    u32 ra=(ua + 0x7fffu + ((ua>>16)&1u))>>16;
    u32 rb=(ub + 0x7fffu + ((ub>>16)&1u))>>16;
    return ra | (rb<<16);
}
__device__ __forceinline__ float lo16(u32 p){ return __uint_as_float(p<<16); }
__device__ __forceinline__ float hi16(u32 p){ return __uint_as_float(p & 0xffff0000u); }

#if __has_builtin(__builtin_amdgcn_fdot2_f32_bf16)
__device__ __forceinline__ float dot2bf(u32 a, u32 b, float c){
    float d;
    asm("v_dot2_f32_bf16 %0, %1, %2, %3" : "=v"(d) : "v"(a), "v"(b), "v"(c));
    return d;
}
#else
__device__ __forceinline__ float dot2bf(u32 a, u32 b, float c){
    return fmaf(hi16(a), hi16(b), fmaf(lo16(a), lo16(b), c));
}
#endif

// async global->LDS, 16B/lane
__device__ __forceinline__ void gll16(const u32* gp, u32* lp){
    __builtin_amdgcn_global_load_lds((const __attribute__((address_space(1))) void*)gp,
                                     (__attribute__((address_space(3))) void*)lp,
                                     16, 0, 0);
}

// ---------- W convert (device fn): fp32 [o][i][jg][c] -> bf16 pairs [ss][il][slot][g]
// slot=j*CB+cb (j 0..15), g=q*O+o, jg=q*16+j, c=cb*8+cw*2, ss=i/IR, il=i%IR
template<int I,int Di,int O,int Do,int IR>
__device__ void conv_dev(const float* __restrict__ W, u32* __restrict__ Wb,
                         int gtid, int gstride){
    constexpr int CB=Di/8, LPO=Do/16, GR=LPO*O, NSL=16*CB;
    const int n = O*I*Do*Di/2;
    for (int t = gtid; t < n; t += gstride){
        int cw = t & 3;
        int u4 = t >> 2;
        int g    = u4 % GR;  int r1 = u4 / GR;
        int slot = r1 % NSL; int r2 = r1 / NSL;
        int il   = r2 % IR;  int ss = r2 / IR;
        int i  = ss*IR + il;
        int j  = slot / CB, cb = slot % CB;
        int o  = g % O,     q  = g / O;
        int jg = q*16 + j;
        int c  = cb*8 + cw*2;
        const float* src = W + ((size_t)(o*I + i)*Do + jg)*Di + c;
        Wb[t] = pk2(src[0], src[1]);
    }
}

// ---------- fused setup: 3 W conversions + x pack, one launch ----------
__global__ void k_setup(const float* __restrict__ W0, const float* __restrict__ W1,
                        const float* __restrict__ W2, const float* __restrict__ x,
                        u32* __restrict__ Wb0, u32* __restrict__ Wb1,
                        u32* __restrict__ Wb2, u32* __restrict__ hb){
    const int gtid = blockIdx.x*blockDim.x + threadIdx.x;
    const int gs   = gridDim.x*blockDim.x;
    conv_dev<128, 8,64,16,4>(W0, Wb0, gtid, gs);
    conv_dev< 64,16,32,32,2>(W1, Wb1, gtid, gs);
    conv_dev< 32,32,10,64,1>(W2, Wb2, gtid, gs);
    for (int t = gtid; t < 1024*512; t += gs){
        float2 f = ((const float2*)x)[t];
        hb[t] = pk2(f.x, f.y);
    }
}

// ---------- k_gemm0: r0 pass = pure GEMM (uniform c), ES=4 (R18-proven) ----------
template<int I,int Di,int O,int Do,int IR>
__global__ __launch_bounds__(512,1) void k_gemm0(
    const u32* __restrict__ Wb, const u32* __restrict__ hsrc,
    u32* __restrict__ ps_out)
{
    constexpr int CB=Di/8, LPO=Do/16, ACT=O*LPO, GR=LPO*O, NSL=16*CB;
    constexpr int SUBS  = 4;
    constexpr int SLICE = IR*NSL*GR*4;      // u32 per sub-slice
    constexpr int WRND  = SLICE/2048;
    static_assert(2*SLICE*4 <= 160*1024, "dbuf slab fits LDS");
    static_assert(SLICE % 2048 == 0, "staging granularity");
    static_assert(8*SUBS*IR == I, "i coverage");
    __shared__ __align__(16) u32 slab[2*SLICE];

    const int tid = threadIdx.x;
    const int w = tid>>6, l = tid&63;
    const int eg = blockIdx.x, sp = blockIdx.y;

    const bool act = l < ACT;
    const int qL = act ? (l%LPO) : 0;
    const int oL = act ? (l/LPO) : 0;
    const int lnoff = qL*O + oL;

    auto stage_w = [&](int sub, int buf){
        const u32* g = Wb + (size_t)(sp*SUBS+sub)*SLICE + tid*4;
        u32* ld = slab + buf*SLICE + w*256;
        #pragma unroll
        for (int rd=0; rd<WRND; ++rd) gll16(g + rd*2048, ld + rd*2048);
    };

    const int e0 = eg*32 + w*4;     // wave owns elements e0..e0+3

    stage_w(0, 0);

    float sacc[4][16];
    #pragma unroll
    for (int k=0;k<4;++k)
        #pragma unroll
        for (int j=0;j<16;++j) sacc[k][j]=0.f;

    __syncthreads();                        // drain stage(0)

    for (int sub=0; sub<SUBS; ++sub){
        if (sub+1 < SUBS) stage_w(sub+1, (sub+1)&1);   // flies under compute
        const uint4* W4 = (const uint4*)(slab + (sub&1)*SLICE);

        #pragma unroll
        for (int il=0; il<IR; ++il){
            const int i = (sp*SUBS+sub)*IR + il;
            #pragma unroll
            for (int cb=0; cb<CB; ++cb){
                u32 hk[4][4];
                #pragma unroll
                for (int k=0;k<4;++k){
                    uint4 hv = *(const uint4*)(hsrc + (size_t)(e0+k)*512 + i*(Di/2) + cb*4);
                    hk[k][0]=hv.x; hk[k][1]=hv.y; hk[k][2]=hv.z; hk[k][3]=hv.w;
                }
                #pragma unroll
                for (int j=0;j<16;++j){
                    uint4 wv = W4[(il*NSL + j*CB + cb)*GR + lnoff];
                    #pragma unroll
                    for (int k=0;k<4;++k){
                        float t = sacc[k][j];
                        t = dot2bf(wv.x, hk[k][0], t);
                        t = dot2bf(wv.y, hk[k][1], t);
                        t = dot2bf(wv.z, hk[k][2], t);
                        t = dot2bf(wv.w, hk[k][3], t);
                        sacc[k][j] = t;
                    }
                }
            }
        }
        __syncthreads();    // drains next-sub DMA + releases buffer
    }

    if (act){
        #pragma unroll
        for (int k=0;k<4;++k){
            u32* pp = ps_out + ((size_t)(sp*1024 + e0 + k))*512 + l*8;
            uint4 o0, o1;
            o0.x=pk2(sacc[k][0],sacc[k][1]);   o0.y=pk2(sacc[k][2],sacc[k][3]);
            o0.z=pk2(sacc[k][4],sacc[k][5]);   o0.w=pk2(sacc[k][6],sacc[k][7]);
            o1.x=pk2(sacc[k][8],sacc[k][9]);   o1.y=pk2(sacc[k][10],sacc[k][11]);
            o1.z=pk2(sacc[k][12],sacc[k][13]); o1.w=pk2(sacc[k][14],sacc[k][15]);
            *(uint4*)pp = o0;
            *(uint4*)(pp+4) = o1;
        }
    }
}

// ---------- contract (r1/r2): ES=4 for 2x W-read amortization + ILP ----------
// Inner loop structure R17-proven; register plan sized to the 256-VGPR cap of
// launch_bounds(512,1): vp32+sacc64+xh64+hk16+addr ~= 195.
// PRO=1: vs = squash(sum/O), persist at sp==0. PRO=2: vs_old + squash(sum).
template<int I,int Di,int O,int Do,int IR,int PRO>
__global__ __launch_bounds__(512,1) void k_contract(
    const u32* __restrict__ Wb, const u32* __restrict__ hsrc,
    u32* __restrict__ vsb, const u32* __restrict__ ps_in,
    u32* __restrict__ ps_out)
{
    constexpr int CB=Di/8, LPO=Do/16, ACT=O*LPO, GR=LPO*O, NSL=16*CB;
    constexpr int ES=4;
    constexpr int SUBS  = 4;
    constexpr int SLICE = IR*NSL*GR*4;
    constexpr int WRND  = SLICE/2048;
    static_assert(2*SLICE*4 <= 160*1024, "dbuf slab fits LDS");
    static_assert(SLICE % 2048 == 0, "staging granularity");
    static_assert(8*SUBS*IR == I, "i coverage");
    __shared__ __align__(16) u32 slab[2*SLICE];

    const int tid = threadIdx.x;
    const int w = tid>>6, l = tid&63;
    const int eg = blockIdx.x, sp = blockIdx.y;

    const bool act = l < ACT;
    const int qL = act ? (l%LPO) : 0;
    const int oL = act ? (l/LPO) : 0;
    const int lnoff = qL*O + oL;

    auto stage_w = [&](int sub, int buf){
        const u32* g = Wb + (size_t)(sp*SUBS+sub)*SLICE + tid*4;
        u32* ld = slab + buf*SLICE + w*256;
        #pragma unroll
        for (int rd=0; rd<WRND; ++rd) gll16(g + rd*2048, ld + rd*2048);
    };

    const int e0 = eg*32 + w*ES;    // wave owns elements e0..e0+3

    stage_w(0, 0);                  // DMA in flight during prologue

    // ---- fused-squash prologue: build vp (packed vs) in registers ----
    u32 vp[ES][8];
    #pragma unroll
    for (int k=0;k<ES;++k){
        const int e = e0+k;
        float s[16];
        #pragma unroll
        for (int j=0;j<16;++j) s[j]=0.f;
        #pragma unroll
        for (int si=0; si<8; ++si){
            const u32* pp = ps_in + ((size_t)(si*1024 + e))*512 + l*8;
            uint4 a = *(const uint4*)pp;
            uint4 b = *(const uint4*)(pp+4);
            u32 q[8]={a.x,a.y,a.z,a.w,b.x,b.y,b.z,b.w};
            #pragma unroll
            for (int t2=0;t2<8;++t2){ s[2*t2]+=lo16(q[t2]); s[2*t2+1]+=hi16(q[t2]); }
        }
        if constexpr (PRO==1){
            #pragma unroll
            for (int j=0;j<16;++j) s[j] *= (1.0f/(float)O);
        }
        float n2=0.f;
        #pragma unroll
        for (int j=0;j<16;++j) n2 += s[j]*s[j];
        if constexpr (LPO>=2) n2 += __shfl_xor(n2,1,64);
        if constexpr (LPO>=4) n2 += __shfl_xor(n2,2,64);
        float nrm   = sqrtf(n2);
        float scale = n2/((1.f+n2)*(nrm+1e-8f));
        float vsv[16];
        if constexpr (PRO==2){
            const u32* vr = vsb + (size_t)e*512 + l*8;
            uint4 a=*(const uint4*)vr; uint4 b=*(const uint4*)(vr+4);
            u32 q[8]={a.x,a.y,a.z,a.w,b.x,b.y,b.z,b.w};
            #pragma unroll
            for (int t2=0;t2<8;++t2){
                vsv[2*t2]   = lo16(q[t2]) + scale*s[2*t2];
                vsv[2*t2+1] = hi16(q[t2]) + scale*s[2*t2+1];
            }
        } else {
            #pragma unroll
            for (int j=0;j<16;++j) vsv[j] = scale*s[j];
        }
        #pragma unroll
        for (int jj=0;jj<8;++jj) vp[k][jj] = pk2(vsv[2*jj], vsv[2*jj+1]);
        if constexpr (PRO==1){
            if (sp==0 && act){      // persist vs for r2 (one writer per element)
                u32* vw = vsb + (size_t)e*512 + l*8;
                #pragma unroll
                for (int jj=0;jj<8;++jj) vw[jj] = vp[k][jj];
            }
        }
    }

    float sacc[ES][16];
    #pragma unroll
    for (int k=0;k<ES;++k)
        #pragma unroll
        for (int j=0;j<16;++j) sacc[k][j]=0.f;

    __syncthreads();                        // drain stage(0)

    for (int sub=0; sub<SUBS; ++sub){
        if (sub+1 < SUBS) stage_w(sub+1, (sub+1)&1);   // flies under compute
        const uint4* W4 = (const uint4*)(slab + (sub&1)*SLICE);

        #pragma unroll
        for (int il=0; il<IR; ++il){
            const int i = (sp*SUBS+sub)*IR + il;

            float xh[ES][16];
            #pragma unroll
            for (int k=0;k<ES;++k)
                #pragma unroll
                for (int j=0;j<16;++j) xh[k][j]=0.f;

            #pragma unroll
            for (int cb=0; cb<CB; ++cb){
                u32 hk[ES][4];
                #pragma unroll
                for (int k=0;k<ES;++k){
                    uint4 hv = *(const uint4*)(hsrc + (size_t)(e0+k)*512 + i*(Di/2) + cb*4);
                    hk[k][0]=hv.x; hk[k][1]=hv.y; hk[k][2]=hv.z; hk[k][3]=hv.w;
                }
                #pragma unroll
                for (int j=0;j<16;++j){
                    uint4 wv = W4[(il*NSL + j*CB + cb)*GR + lnoff];
                    #pragma unroll
                    for (int k=0;k<ES;++k){
                        float t = xh[k][j];
                        t = dot2bf(wv.x, hk[k][0], t);
                        t = dot2bf(wv.y, hk[k][1], t);
                        t = dot2bf(wv.z, hk[k][2], t);
                        t = dot2bf(wv.w, hk[k][3], t);
                        xh[k][j] = t;
                    }
                }
            }

            float cc[ES];
            #pragma unroll
            for (int k=0;k<ES;++k){
                float lp=0.f;
                #pragma unroll
                for (int jj=0;jj<8;++jj)
                    lp += lo16(vp[k][jj])*xh[k][2*jj] + hi16(vp[k][jj])*xh[k][2*jj+1];
                if constexpr (LPO>=2) lp += __shfl_xor(lp,1,64);
                if constexpr (LPO>=4) lp += __shfl_xor(lp,2,64);
                float ev = act ? __expf(lp) : 0.f;
                float tot = ev;                  // each o counted LPO times
                tot+=__shfl_xor(tot,1,64);  tot+=__shfl_xor(tot,2,64);
                tot+=__shfl_xor(tot,4,64);  tot+=__shfl_xor(tot,8,64);
                tot+=__shfl_xor(tot,16,64); tot+=__shfl_xor(tot,32,64);
                cc[k] = ev*(float)LPO/tot;
            }
            #pragma unroll
            for (int k=0;k<ES;++k)
                #pragma unroll
                for (int j=0;j<16;++j) sacc[k][j] += cc[k]*xh[k][j];
        }
        __syncthreads();    // drains next-sub DMA + releases buffer
    }

    if (act){
        #pragma unroll
        for (int k=0;k<ES;++k){
            u32* pp = ps_out + ((size_t)(sp*1024 + e0 + k))*512 + l*8;
            uint4 o0, o1;
            o0.x=pk2(sacc[k][0],sacc[k][1]);   o0.y=pk2(sacc[k][2],sacc[k][3]);
            o0.z=pk2(sacc[k][4],sacc[k][5]);   o0.w=pk2(sacc[k][6],sacc[k][7]);
            o1.x=pk2(sacc[k][8],sacc[k][9]);   o1.y=pk2(sacc[k][10],sacc[k][11]);
            o1.z=pk2(sacc[k][12],sacc[k][13]); o1.w=pk2(sacc[k][14],sacc[k][15]);
            *(uint4*)pp = o0;
            *(uint4*)(pp+4) = o1;
        }
    }
}

// ---------- squash tail: MODE 2 = hnext from ps, MODE 3 = out = ||v|| ----------
template<int O,int Do,int MODE>
__global__ __launch_bounds__(256) void k_squash(
    const u32* __restrict__ ps, void* __restrict__ dst)
{
    constexpr int LPO=Do/16, ACT=O*LPO;
    const int tid=threadIdx.x, w=tid>>6, l=tid&63;
    const int e = blockIdx.x*4 + w;
    const bool act = l < ACT;
    const int oL = act ? (l/LPO) : 0;

    float s[16];
    #pragma unroll
    for (int j=0;j<16;++j) s[j]=0.f;
    #pragma unroll
    for (int si=0; si<8; ++si){
        const u32* pp = ps + ((size_t)(si*1024 + e))*512 + l*8;
        uint4 a = *(const uint4*)pp;
        uint4 b = *(const uint4*)(pp+4);
        u32 q[8] = {a.x,a.y,a.z,a.w,b.x,b.y,b.z,b.w};
        #pragma unroll
        for (int k=0;k<8;++k){ s[2*k] += lo16(q[k]); s[2*k+1] += hi16(q[k]); }
    }
    float n2=0.f;
    #pragma unroll
    for (int j=0;j<16;++j) n2 += s[j]*s[j];
    if constexpr (LPO>=2) n2 += __shfl_xor(n2,1,64);
    if constexpr (LPO>=4) n2 += __shfl_xor(n2,2,64);
    float nrm   = sqrtf(n2);
    float scale = n2/((1.f+n2)*(nrm+1e-8f));

    if constexpr (MODE==2){
        if (act){
            u32* hp = (u32*)dst + (size_t)e*512 + l*8;
            #pragma unroll
            for (int k=0;k<8;++k) hp[k] = pk2(scale*s[2*k], scale*s[2*k+1]);
        }
    } else {
        float q=0.f;
        #pragma unroll
        for (int j=0;j<16;++j){ float vj=scale*s[j]; q += vj*vj; }
        if constexpr (LPO>=2) q += __shfl_xor(q,1,64);
        if constexpr (LPO>=4) q += __shfl_xor(q,2,64);
        if (act && (l%LPO)==0)
            ((float*)dst)[(size_t)e*O + oL] = sqrtf(q);
    }
}

// ---------------- fallback (round-2 kernel, known-pass) ----------------
template<int I, int Di, int O, int Do, bool FINAL>
__device__ __forceinline__ void fb_layer(const float* __restrict__ W, float* __restrict__ hl,
                                         float* __restrict__ out, int e, int l) {
    constexpr int LPO = Do / 16;
    constexpr int ACT = O * LPO;
    const int o  = l / LPO;
    const int d0 = (l % LPO) * 16;
    const bool act = (l < ACT);
    float vs[16];
    #pragma unroll
    for (int j = 0; j < 16; ++j) vs[j] = 0.f;
    for (int r = 0; r < 3; ++r) {
        float sacc[16];
        #pragma unroll
        for (int j = 0; j < 16; ++j) sacc[j] = 0.f;
        for (int i = 0; i < I; ++i) {
            if ((i & 15) == 0) __syncthreads();
            float xh[16];
            #pragma unroll
            for (int j = 0; j < 16; ++j) xh[j] = 0.f;
            if (act) {
                const float* wb = W + ((size_t)(o * I + i) * Do + d0) * Di;
                #pragma unroll
                for (int j = 0; j < 16; ++j) {
                    const float4* wr = (const float4*)(wb + j * Di);
                    float acc = 0.f;
                    #pragma unroll
                    for (int c4 = 0; c4 < Di / 4; ++c4) {
                        float4 wv = wr[c4];
                        float4 hv = *(const float4*)(hl + i * Di + c4 * 4);
                        acc += wv.x*hv.x + wv.y*hv.y + wv.z*hv.z + wv.w*hv.w;
                    }
                    xh[j] = acc;
                }
            }
            float cc;
            if (r == 0) cc = 1.0f;
            else {
                float lp = 0.f;
                #pragma unroll
                for (int j = 0; j < 16; ++j) lp += vs[j] * xh[j];
                if constexpr (LPO >= 2) lp += __shfl_xor(lp, 1, 64);
                if constexpr (LPO >= 4) lp += __shfl_xor(lp, 2, 64);
                float ev = act ? __expf(lp) : 0.f;
                float tot = ev;
                tot += __shfl_xor(tot,1,64); tot += __shfl_xor(tot,2,64);
                tot += __shfl_xor(tot,4,64); tot += __shfl_xor(tot,8,64);
                tot += __shfl_xor(tot,16,64); tot += __shfl_xor(tot,32,64);
                cc = ev * (float)LPO / tot;
            }
            #pragma unroll
            for (int j = 0; j < 16; ++j) sacc[j] += cc * xh[j];
        }
        if (r == 0) {
            #pragma unroll
            for (int j = 0; j < 16; ++j) sacc[j] *= (1.0f / O);
        }
        float n2 = 0.f;
        #pragma unroll
        for (int j = 0; j < 16; ++j) n2 += sacc[j] * sacc[j];
        if constexpr (LPO >= 2) n2 += __shfl_xor(n2, 1, 64);
        if constexpr (LPO >= 4) n2 += __shfl_xor(n2, 2, 64);
        float nrm = sqrtf(n2);
        float scale = n2 / ((1.f + n2) * (nrm + 1e-8f));
        if (r < 2) {
            #pragma unroll
            for (int j = 0; j < 16; ++j) vs[j] += scale * sacc[j];
        } else {
            if constexpr (FINAL) {
                float q = 0.f;
                #pragma unroll
                for (int j = 0; j < 16; ++j) { float vj = scale*sacc[j]; q += vj*vj; }
                if constexpr (LPO >= 2) q += __shfl_xor(q, 1, 64);
                if constexpr (LPO >= 4) q += __shfl_xor(q, 2, 64);
                if (act && (l % LPO) == 0) out[(size_t)e * O + o] = sqrtf(q);
            } else {
                __syncthreads();
                if (act) {
                    #pragma unroll
                    for (int j = 0; j < 16; ++j) hl[o * Do + d0 + j] = scale * sacc[j];
                }
                __syncthreads();
            }
        }
    }
}

__global__ __launch_bounds__(256) void fb_caps(const float* __restrict__ x,
                                               const float* __restrict__ W0,
                                               const float* __restrict__ W1,
                                               const float* __restrict__ W2,
                                               float* __restrict__ out) {
    __shared__ float hsh[4][1024];
    const int w = threadIdx.x >> 6;
    const int l = threadIdx.x & 63;
    const int e = blockIdx.x * 4 + w;
    float* hl = hsh[w];
    const float4* xr = (const float4*)(x + (size_t)e * 1024);
    float4* h4 = (float4*)hl;
    #pragma unroll
    for (int k = 0; k < 4; ++k) h4[l + 64 * k] = xr[l + 64 * k];
    __syncthreads();
    fb_layer<128, 8, 64, 16, false>(W0, hl, out, e, l);
    fb_layer<64, 16, 32, 32, false>(W1, hl, out, e, l);
    fb_layer<32, 32, 10, 64, true >(W2, hl, out, e, l);
}

extern "C" void kernel_launch(void* const* d_in, const int* in_sizes, int n_in,
                              void* d_out, int out_size, void* d_ws, size_t ws_size,
                              hipStream_t stream) {
    const float* x  = (const float*)d_in[0];   // [1024,1024]
    const float* W0 = (const float*)d_in[1];   // [64,128,16,8]
    const float* W1 = (const float*)d_in[2];   // [32,64,32,16]
    const float* W2 = (const float*)d_in[3];   // [10,32,64,32]
    float* out = (float*)d_out;                // [1024,10]

    const size_t DW0 = 524288, DW1 = 524288, DW2 = 327680;   // u32
    const size_t DPS = (size_t)8*1024*512;                   // 4194304 u32 per ps buf
    const size_t DVS = (size_t)1024*512;                     // vs (bf16 pairs)
    const size_t DH  = (size_t)1024*512;                     // shared h buffer
    const size_t need = (DW0+DW1+DW2 + 2*DPS + DVS + DH)*4;  // 43,253,760 B

    if (ws_size < need) {                       // safety net: proven slow path
        fb_caps<<<256, 256, 0, stream>>>(x, W0, W1, W2, out);
        return;
    }

    u32* Wb0 = (u32*)d_ws;
    u32* Wb1 = Wb0 + DW0;
    u32* Wb2 = Wb1 + DW1;
    u32* psA = Wb2 + DW2;
    u32* psB = psA + DPS;
    u32* vs  = psB + DPS;
    u32* hb  = vs  + DVS;   // x-packed, then h1, then h2 (disjoint live ranges)

    k_setup<<<1024, 256, 0, stream>>>(W0, W1, W2, x, Wb0, Wb1, Wb2, hb);

    dim3 g0(32, 8);   // k_gemm0 and k_contract: 32 el-groups x 8 slices

    // layer 0: I=128 Di=8 O=64 Do=16, IR=4 (2 x 64KB dbuf)
    k_gemm0<128,8,64,16,4><<<g0,512,0,stream>>>(Wb0, hb, psA);
    k_contract<128,8,64,16,4,1><<<g0,512,0,stream>>>(Wb0, hb, vs, psA, psB);
    k_contract<128,8,64,16,4,2><<<g0,512,0,stream>>>(Wb0, hb, vs, psB, psA);
    k_squash<64,16,2><<<256,256,0,stream>>>(psA, hb);      // h1 (overwrites x-pack)

    // layer 1: I=64 Di=16 O=32 Do=32, IR=2 (2 x 64KB dbuf)
    k_gemm0<64,16,32,32,2><<<g0,512,0,stream>>>(Wb1, hb, psA);
    k_contract<64,16,32,32,2,1><<<g0,512,0,stream>>>(Wb1, hb, vs, psA, psB);
    k_contract<64,16,32,32,2,2><<<g0,512,0,stream>>>(Wb1, hb, vs, psB, psA);
    k_squash<32,32,2><<<256,256,0,stream>>>(psA, hb);      // h2 (overwrites h1)

    // layer 2: I=32 Di=32 O=10 Do=64, IR=1 (2 x 40KB dbuf)
    k_gemm0<32,32,10,64,1><<<g0,512,0,stream>>>(Wb2, hb, psA);
    k_contract<32,32,10,64,1,1><<<g0,512,0,stream>>>(Wb2, hb, vs, psA, psB);
    k_contract<32,32,10,64,1,2><<<g0,512,0,stream>>>(Wb2, hb, vs, psB, psA);
    k_squash<10,64,3><<<256,256,0,stream>>>(psA, out);     // ||v2||
}

// Round 20
// 445.377 us; speedup vs baseline: 1.5391x; 1.5391x over previous
//
#include <hip/hip_runtime.h>
#include <math.h>

typedef unsigned int u32;

// ---------- bf16 helpers ----------
__device__ __forceinline__ u32 pk2(float a, float b){
    u32 ua=__float_as_uint(a), ub=__float_as_uint(b);
    u32 ra=(ua + 0x7fffu + ((ua>>16)&1u))>>16;
    u32 rb=(ub + 0x7fffu + ((ub>>16)&1u))>>16;
    return ra | (rb<<16);
}
__device__ __forceinline__ float lo16(u32 p){ return __uint_as_float(p<<16); }
__device__ __forceinline__ float hi16(u32 p){ return __uint_as_float(p & 0xffff0000u); }

#if __has_builtin(__builtin_amdgcn_fdot2_f32_bf16)
__device__ __forceinline__ float dot2bf(u32 a, u32 b, float c){
    float d;
    asm("v_dot2_f32_bf16 %0, %1, %2, %3" : "=v"(d) : "v"(a), "v"(b), "v"(c));
    return d;
}
#else
__device__ __forceinline__ float dot2bf(u32 a, u32 b, float c){
    return fmaf(hi16(a), hi16(b), fmaf(lo16(a), lo16(b), c));
}
#endif

// async global->LDS, 16B/lane
__device__ __forceinline__ void gll16(const u32* gp, u32* lp){
    __builtin_amdgcn_global_load_lds((const __attribute__((address_space(1))) void*)gp,
                                     (__attribute__((address_space(3))) void*)lp,
                                     16, 0, 0);
}

// ---------- W convert (device fn): fp32 [o][i][jg][c] -> bf16 pairs [ss][il][slot][g]
// slot=j*CB+cb (j 0..15), g=q*O+o, jg=q*16+j, c=cb*8+cw*2, ss=i/IR, il=i%IR
template<int I,int Di,int O,int Do,int IR>
__device__ void conv_dev(const float* __restrict__ W, u32* __restrict__ Wb,
                         int gtid, int gstride){
    constexpr int CB=Di/8, LPO=Do/16, GR=LPO*O, NSL=16*CB;
    const int n = O*I*Do*Di/2;
    for (int t = gtid; t < n; t += gstride){
        int cw = t & 3;
        int u4 = t >> 2;
        int g    = u4 % GR;  int r1 = u4 / GR;
        int slot = r1 % NSL; int r2 = r1 / NSL;
        int il   = r2 % IR;  int ss = r2 / IR;
        int i  = ss*IR + il;
        int j  = slot / CB, cb = slot % CB;
        int o  = g % O,     q  = g / O;
        int jg = q*16 + j;
        int c  = cb*8 + cw*2;
        const float* src = W + ((size_t)(o*I + i)*Do + jg)*Di + c;
        Wb[t] = pk2(src[0], src[1]);
    }
}

// ---------- fused setup: 3 W conversions + x pack, one launch ----------
__global__ void k_setup(const float* __restrict__ W0, const float* __restrict__ W1,
                        const float* __restrict__ W2, const float* __restrict__ x,
                        u32* __restrict__ Wb0, u32* __restrict__ Wb1,
                        u32* __restrict__ Wb2, u32* __restrict__ hb){
    const int gtid = blockIdx.x*blockDim.x + threadIdx.x;
    const int gs   = gridDim.x*blockDim.x;
    conv_dev<128, 8,64,16,4>(W0, Wb0, gtid, gs);
    conv_dev< 64,16,32,32,2>(W1, Wb1, gtid, gs);
    conv_dev< 32,32,10,64,1>(W2, Wb2, gtid, gs);
    for (int t = gtid; t < 1024*512; t += gs){
        float2 f = ((const float2*)x)[t];
        hb[t] = pk2(f.x, f.y);
    }
}

// ---------- k_gemm0: r0 pass = pure GEMM (uniform c), ES=4 (R18-proven) ----------
template<int I,int Di,int O,int Do,int IR>
__global__ __launch_bounds__(512,1) void k_gemm0(
    const u32* __restrict__ Wb, const u32* __restrict__ hsrc,
    u32* __restrict__ ps_out)
{
    constexpr int CB=Di/8, LPO=Do/16, ACT=O*LPO, GR=LPO*O, NSL=16*CB;
    constexpr int SUBS  = 4;
    constexpr int SLICE = IR*NSL*GR*4;      // u32 per sub-slice
    constexpr int WRND  = SLICE/2048;
    static_assert(2*SLICE*4 <= 160*1024, "dbuf slab fits LDS");
    static_assert(SLICE % 2048 == 0, "staging granularity");
    static_assert(8*SUBS*IR == I, "i coverage");
    __shared__ __align__(16) u32 slab[2*SLICE];

    const int tid = threadIdx.x;
    const int w = tid>>6, l = tid&63;
    const int eg = blockIdx.x, sp = blockIdx.y;

    const bool act = l < ACT;
    const int qL = act ? (l%LPO) : 0;
    const int oL = act ? (l/LPO) : 0;
    const int lnoff = qL*O + oL;

    auto stage_w = [&](int sub, int buf){
        const u32* g = Wb + (size_t)(sp*SUBS+sub)*SLICE + tid*4;
        u32* ld = slab + buf*SLICE + w*256;
        #pragma unroll
        for (int rd=0; rd<WRND; ++rd) gll16(g + rd*2048, ld + rd*2048);
    };

    const int e0 = eg*32 + w*4;     // wave owns elements e0..e0+3

    stage_w(0, 0);

    float sacc[4][16];
    #pragma unroll
    for (int k=0;k<4;++k)
        #pragma unroll
        for (int j=0;j<16;++j) sacc[k][j]=0.f;

    __syncthreads();                        // drain stage(0)

    for (int sub=0; sub<SUBS; ++sub){
        if (sub+1 < SUBS) stage_w(sub+1, (sub+1)&1);   // flies under compute
        const uint4* W4 = (const uint4*)(slab + (sub&1)*SLICE);

        #pragma unroll
        for (int il=0; il<IR; ++il){
            const int i = (sp*SUBS+sub)*IR + il;
            #pragma unroll
            for (int cb=0; cb<CB; ++cb){
                u32 hk[4][4];
                #pragma unroll
                for (int k=0;k<4;++k){
                    uint4 hv = *(const uint4*)(hsrc + (size_t)(e0+k)*512 + i*(Di/2) + cb*4);
                    hk[k][0]=hv.x; hk[k][1]=hv.y; hk[k][2]=hv.z; hk[k][3]=hv.w;
                }
                #pragma unroll
                for (int j=0;j<16;++j){
                    uint4 wv = W4[(il*NSL + j*CB + cb)*GR + lnoff];
                    #pragma unroll
                    for (int k=0;k<4;++k){
                        float t = sacc[k][j];
                        t = dot2bf(wv.x, hk[k][0], t);
                        t = dot2bf(wv.y, hk[k][1], t);
                        t = dot2bf(wv.z, hk[k][2], t);
                        t = dot2bf(wv.w, hk[k][3], t);
                        sacc[k][j] = t;
                    }
                }
            }
        }
        __syncthreads();    // drains next-sub DMA + releases buffer
    }

    if (act){
        #pragma unroll
        for (int k=0;k<4;++k){
            u32* pp = ps_out + ((size_t)(sp*1024 + e0 + k))*512 + l*8;
            uint4 o0, o1;
            o0.x=pk2(sacc[k][0],sacc[k][1]);   o0.y=pk2(sacc[k][2],sacc[k][3]);
            o0.z=pk2(sacc[k][4],sacc[k][5]);   o0.w=pk2(sacc[k][6],sacc[k][7]);
            o1.x=pk2(sacc[k][8],sacc[k][9]);   o1.y=pk2(sacc[k][10],sacc[k][11]);
            o1.z=pk2(sacc[k][12],sacc[k][13]); o1.w=pk2(sacc[k][14],sacc[k][15]);
            *(uint4*)pp = o0;
            *(uint4*)(pp+4) = o1;
        }
    }
}

// ---------- contract (r1/r2): ES=2, R17/R18-proven (120 VGPR, no spill) ----------
// PRO=1: vs = squash(sum/O), persist at sp==0. PRO=2: vs_old + squash(sum).
template<int I,int Di,int O,int Do,int IR,int PRO>
__global__ __launch_bounds__(512,1) void k_contract(
    const u32* __restrict__ Wb, const u32* __restrict__ hsrc,
    u32* __restrict__ vsb, const u32* __restrict__ ps_in,
    u32* __restrict__ ps_out)
{
    constexpr int CB=Di/8, LPO=Do/16, ACT=O*LPO, GR=LPO*O, NSL=16*CB;
    constexpr int SUBS  = 4;
    constexpr int SLICE = IR*NSL*GR*4;
    constexpr int WRND  = SLICE/2048;
    static_assert(2*SLICE*4 <= 160*1024, "dbuf slab fits LDS");
    static_assert(SLICE % 2048 == 0, "staging granularity");
    static_assert(8*SUBS*IR == I, "i coverage");
    __shared__ __align__(16) u32 slab[2*SLICE];

    const int tid = threadIdx.x;
    const int w = tid>>6, l = tid&63;
    const int eg = blockIdx.x, sp = blockIdx.y;

    const bool act = l < ACT;
    const int qL = act ? (l%LPO) : 0;
    const int oL = act ? (l/LPO) : 0;
    const int lnoff = qL*O + oL;

    auto stage_w = [&](int sub, int buf){
        const u32* g = Wb + (size_t)(sp*SUBS+sub)*SLICE + tid*4;
        u32* ld = slab + buf*SLICE + w*256;
        #pragma unroll
        for (int rd=0; rd<WRND; ++rd) gll16(g + rd*2048, ld + rd*2048);
    };

    const int e0 = eg*16 + w*2;     // wave owns elements e0, e0+1

    stage_w(0, 0);                  // DMA in flight during prologue

    // ---- fused-squash prologue: build vp (packed vs) in registers ----
    u32 vp[2][8];
    #pragma unroll
    for (int k=0;k<2;++k){
        const int e = e0+k;
        float s[16];
        #pragma unroll
        for (int j=0;j<16;++j) s[j]=0.f;
        #pragma unroll
        for (int si=0; si<8; ++si){
            const u32* pp = ps_in + ((size_t)(si*1024 + e))*512 + l*8;
            uint4 a = *(const uint4*)pp;
            uint4 b = *(const uint4*)(pp+4);
            u32 q[8]={a.x,a.y,a.z,a.w,b.x,b.y,b.z,b.w};
            #pragma unroll
            for (int t2=0;t2<8;++t2){ s[2*t2]+=lo16(q[t2]); s[2*t2+1]+=hi16(q[t2]); }
        }
        if constexpr (PRO==1){
            #pragma unroll
            for (int j=0;j<16;++j) s[j] *= (1.0f/(float)O);
        }
        float n2=0.f;
        #pragma unroll
        for (int j=0;j<16;++j) n2 += s[j]*s[j];
        if constexpr (LPO>=2) n2 += __shfl_xor(n2,1,64);
        if constexpr (LPO>=4) n2 += __shfl_xor(n2,2,64);
        float nrm   = sqrtf(n2);
        float scale = n2/((1.f+n2)*(nrm+1e-8f));
        float vsv[16];
        if constexpr (PRO==2){
            const u32* vr = vsb + (size_t)e*512 + l*8;
            uint4 a=*(const uint4*)vr; uint4 b=*(const uint4*)(vr+4);
            u32 q[8]={a.x,a.y,a.z,a.w,b.x,b.y,b.z,b.w};
            #pragma unroll
            for (int t2=0;t2<8;++t2){
                vsv[2*t2]   = lo16(q[t2]) + scale*s[2*t2];
                vsv[2*t2+1] = hi16(q[t2]) + scale*s[2*t2+1];
            }
        } else {
            #pragma unroll
            for (int j=0;j<16;++j) vsv[j] = scale*s[j];
        }
        #pragma unroll
        for (int jj=0;jj<8;++jj) vp[k][jj] = pk2(vsv[2*jj], vsv[2*jj+1]);
        if constexpr (PRO==1){
            if (sp==0 && act){      // persist vs for r2 (one writer per element)
                u32* vw = vsb + (size_t)e*512 + l*8;
                #pragma unroll
                for (int jj=0;jj<8;++jj) vw[jj] = vp[k][jj];
            }
        }
    }

    float sacc[2][16];
    #pragma unroll
    for (int k=0;k<2;++k)
        #pragma unroll
        for (int j=0;j<16;++j) sacc[k][j]=0.f;

    __syncthreads();                        // drain stage(0)

    for (int sub=0; sub<SUBS; ++sub){
        if (sub+1 < SUBS) stage_w(sub+1, (sub+1)&1);   // flies under compute
        const uint4* W4 = (const uint4*)(slab + (sub&1)*SLICE);

        #pragma unroll
        for (int il=0; il<IR; ++il){
            const int i = (sp*SUBS+sub)*IR + il;

            float xh[2][16];
            #pragma unroll
            for (int k=0;k<2;++k)
                #pragma unroll
                for (int j=0;j<16;++j) xh[k][j]=0.f;

            #pragma unroll
            for (int cb=0; cb<CB; ++cb){
                u32 hk[2][4];
                #pragma unroll
                for (int k=0;k<2;++k){
                    uint4 hv = *(const uint4*)(hsrc + (size_t)(e0+k)*512 + i*(Di/2) + cb*4);
                    hk[k][0]=hv.x; hk[k][1]=hv.y; hk[k][2]=hv.z; hk[k][3]=hv.w;
                }
                #pragma unroll
                for (int j=0;j<16;++j){
                    uint4 wv = W4[(il*NSL + j*CB + cb)*GR + lnoff];
                    #pragma unroll
                    for (int k=0;k<2;++k){
                        float t = xh[k][j];
                        t = dot2bf(wv.x, hk[k][0], t);
                        t = dot2bf(wv.y, hk[k][1], t);
                        t = dot2bf(wv.z, hk[k][2], t);
                        t = dot2bf(wv.w, hk[k][3], t);
                        xh[k][j] = t;
                    }
                }
            }

            float cc[2];
            #pragma unroll
            for (int k=0;k<2;++k){
                float lp=0.f;
                #pragma unroll
                for (int jj=0;jj<8;++jj)
                    lp += lo16(vp[k][jj])*xh[k][2*jj] + hi16(vp[k][jj])*xh[k][2*jj+1];
                if constexpr (LPO>=2) lp += __shfl_xor(lp,1,64);
                if constexpr (LPO>=4) lp += __shfl_xor(lp,2,64);
                float ev = act ? __expf(lp) : 0.f;
                float tot = ev;                  // each o counted LPO times
                tot+=__shfl_xor(tot,1,64);  tot+=__shfl_xor(tot,2,64);
                tot+=__shfl_xor(tot,4,64);  tot+=__shfl_xor(tot,8,64);
                tot+=__shfl_xor(tot,16,64); tot+=__shfl_xor(tot,32,64);
                cc[k] = ev*(float)LPO/tot;
            }
            #pragma unroll
            for (int k=0;k<2;++k)
                #pragma unroll
                for (int j=0;j<16;++j) sacc[k][j] += cc[k]*xh[k][j];
        }
        __syncthreads();    // drains next-sub DMA + releases buffer
    }

    if (act){
        #pragma unroll
        for (int k=0;k<2;++k){
            u32* pp = ps_out + ((size_t)(sp*1024 + e0 + k))*512 + l*8;
            uint4 o0, o1;
            o0.x=pk2(sacc[k][0],sacc[k][1]);   o0.y=pk2(sacc[k][2],sacc[k][3]);
            o0.z=pk2(sacc[k][4],sacc[k][5]);   o0.w=pk2(sacc[k][6],sacc[k][7]);
            o1.x=pk2(sacc[k][8],sacc[k][9]);   o1.y=pk2(sacc[k][10],sacc[k][11]);
            o1.z=pk2(sacc[k][12],sacc[k][13]); o1.w=pk2(sacc[k][14],sacc[k][15]);
            *(uint4*)pp = o0;
            *(uint4*)(pp+4) = o1;
        }
    }
}

// ---------- squash tail: MODE 2 = hnext from ps, MODE 3 = out = ||v|| ----------
template<int O,int Do,int MODE>
__global__ __launch_bounds__(256) void k_squash(
    const u32* __restrict__ ps, void* __restrict__ dst)
{
    constexpr int LPO=Do/16, ACT=O*LPO;
    const int tid=threadIdx.x, w=tid>>6, l=tid&63;
    const int e = blockIdx.x*4 + w;
    const bool act = l < ACT;
    const int oL = act ? (l/LPO) : 0;

    float s[16];
    #pragma unroll
    for (int j=0;j<16;++j) s[j]=0.f;
    #pragma unroll
    for (int si=0; si<8; ++si){
        const u32* pp = ps + ((size_t)(si*1024 + e))*512 + l*8;
        uint4 a = *(const uint4*)pp;
        uint4 b = *(const uint4*)(pp+4);
        u32 q[8] = {a.x,a.y,a.z,a.w,b.x,b.y,b.z,b.w};
        #pragma unroll
        for (int k=0;k<8;++k){ s[2*k] += lo16(q[k]); s[2*k+1] += hi16(q[k]); }
    }
    float n2=0.f;
    #pragma unroll
    for (int j=0;j<16;++j) n2 += s[j]*s[j];
    if constexpr (LPO>=2) n2 += __shfl_xor(n2,1,64);
    if constexpr (LPO>=4) n2 += __shfl_xor(n2,2,64);
    float nrm   = sqrtf(n2);
    float scale = n2/((1.f+n2)*(nrm+1e-8f));

    if constexpr (MODE==2){
        if (act){
            u32* hp = (u32*)dst + (size_t)e*512 + l*8;
            #pragma unroll
            for (int k=0;k<8;++k) hp[k] = pk2(scale*s[2*k], scale*s[2*k+1]);
        }
    } else {
        float q=0.f;
        #pragma unroll
        for (int j=0;j<16;++j){ float vj=scale*s[j]; q += vj*vj; }
        if constexpr (LPO>=2) q += __shfl_xor(q,1,64);
        if constexpr (LPO>=4) q += __shfl_xor(q,2,64);
        if (act && (l%LPO)==0)
            ((float*)dst)[(size_t)e*O + oL] = sqrtf(q);
    }
}

// ---------------- fallback (round-2 kernel, known-pass) ----------------
template<int I, int Di, int O, int Do, bool FINAL>
__device__ __forceinline__ void fb_layer(const float* __restrict__ W, float* __restrict__ hl,
                                         float* __restrict__ out, int e, int l) {
    constexpr int LPO = Do / 16;
    constexpr int ACT = O * LPO;
    const int o  = l / LPO;
    const int d0 = (l % LPO) * 16;
    const bool act = (l < ACT);
    float vs[16];
    #pragma unroll
    for (int j = 0; j < 16; ++j) vs[j] = 0.f;
    for (int r = 0; r < 3; ++r) {
        float sacc[16];
        #pragma unroll
        for (int j = 0; j < 16; ++j) sacc[j] = 0.f;
        for (int i = 0; i < I; ++i) {
            if ((i & 15) == 0) __syncthreads();
            float xh[16];
            #pragma unroll
            for (int j = 0; j < 16; ++j) xh[j] = 0.f;
            if (act) {
                const float* wb = W + ((size_t)(o * I + i) * Do + d0) * Di;
                #pragma unroll
                for (int j = 0; j < 16; ++j) {
                    const float4* wr = (const float4*)(wb + j * Di);
                    float acc = 0.f;
                    #pragma unroll
                    for (int c4 = 0; c4 < Di / 4; ++c4) {
                        float4 wv = wr[c4];
                        float4 hv = *(const float4*)(hl + i * Di + c4 * 4);
                        acc += wv.x*hv.x + wv.y*hv.y + wv.z*hv.z + wv.w*hv.w;
                    }
                    xh[j] = acc;
                }
            }
            float cc;
            if (r == 0) cc = 1.0f;
            else {
                float lp = 0.f;
                #pragma unroll
                for (int j = 0; j < 16; ++j) lp += vs[j] * xh[j];
                if constexpr (LPO >= 2) lp += __shfl_xor(lp, 1, 64);
                if constexpr (LPO >= 4) lp += __shfl_xor(lp, 2, 64);
                float ev = act ? __expf(lp) : 0.f;
                float tot = ev;
                tot += __shfl_xor(tot,1,64); tot += __shfl_xor(tot,2,64);
                tot += __shfl_xor(tot,4,64); tot += __shfl_xor(tot,8,64);
                tot += __shfl_xor(tot,16,64); tot += __shfl_xor(tot,32,64);
                cc = ev * (float)LPO / tot;
            }
            #pragma unroll
            for (int j = 0; j < 16; ++j) sacc[j] += cc * xh[j];
        }
        if (r == 0) {
            #pragma unroll
            for (int j = 0; j < 16; ++j) sacc[j] *= (1.0f / O);
        }
        float n2 = 0.f;
        #pragma unroll
        for (int j = 0; j < 16; ++j) n2 += sacc[j] * sacc[j];
        if constexpr (LPO >= 2) n2 += __shfl_xor(n2, 1, 64);
        if constexpr (LPO >= 4) n2 += __shfl_xor(n2, 2, 64);
        float nrm = sqrtf(n2);
        float scale = n2 / ((1.f + n2) * (nrm + 1e-8f));
        if (r < 2) {
            #pragma unroll
            for (int j = 0; j < 16; ++j) vs[j] += scale * sacc[j];
        } else {
            if constexpr (FINAL) {
                float q = 0.f;
                #pragma unroll
                for (int j = 0; j < 16; ++j) { float vj = scale*sacc[j]; q += vj*vj; }
                if constexpr (LPO >= 2) q += __shfl_xor(q, 1, 64);
                if constexpr (LPO >= 4) q += __shfl_xor(q, 2, 64);
                if (act && (l % LPO) == 0) out[(size_t)e * O + o] = sqrtf(q);
            } else {
                __syncthreads();
                if (act) {
                    #pragma unroll
                    for (int j = 0; j < 16; ++j) hl[o * Do + d0 + j] = scale * sacc[j];
                }
                __syncthreads();
            }
        }
    }
}

__global__ __launch_bounds__(256) void fb_caps(const float* __restrict__ x,
                                               const float* __restrict__ W0,
                                               const float* __restrict__ W1,
                                               const float* __restrict__ W2,
                                               float* __restrict__ out) {
    __shared__ float hsh[4][1024];
    const int w = threadIdx.x >> 6;
    const int l = threadIdx.x & 63;
    const int e = blockIdx.x * 4 + w;
    float* hl = hsh[w];
    const float4* xr = (const float4*)(x + (size_t)e * 1024);
    float4* h4 = (float4*)hl;
    #pragma unroll
    for (int k = 0; k < 4; ++k) h4[l + 64 * k] = xr[l + 64 * k];
    __syncthreads();
    fb_layer<128, 8, 64, 16, false>(W0, hl, out, e, l);
    fb_layer<64, 16, 32, 32, false>(W1, hl, out, e, l);
    fb_layer<32, 32, 10, 64, true >(W2, hl, out, e, l);
}

extern "C" void kernel_launch(void* const* d_in, const int* in_sizes, int n_in,
                              void* d_out, int out_size, void* d_ws, size_t ws_size,
                              hipStream_t stream) {
    const float* x  = (const float*)d_in[0];   // [1024,1024]
    const float* W0 = (const float*)d_in[1];   // [64,128,16,8]
    const float* W1 = (const float*)d_in[2];   // [32,64,32,16]
    const float* W2 = (const float*)d_in[3];   // [10,32,64,32]
    float* out = (float*)d_out;                // [1024,10]

    const size_t DW0 = 524288, DW1 = 524288, DW2 = 327680;   // u32
    const size_t DPS = (size_t)8*1024*512;                   // 4194304 u32 per ps buf
    const size_t DVS = (size_t)1024*512;                     // vs (bf16 pairs)
    const size_t DH  = (size_t)1024*512;                     // shared h buffer
    const size_t need = (DW0+DW1+DW2 + 2*DPS + DVS + DH)*4;  // 43,253,760 B

    if (ws_size < need) {                       // safety net: proven slow path
        fb_caps<<<256, 256, 0, stream>>>(x, W0, W1, W2, out);
        return;
    }

    u32* Wb0 = (u32*)d_ws;
    u32* Wb1 = Wb0 + DW0;
    u32* Wb2 = Wb1 + DW1;
    u32* psA = Wb2 + DW2;
    u32* psB = psA + DPS;
    u32* vs  = psB + DPS;
    u32* hb  = vs  + DVS;   // x-packed, then h1, then h2 (disjoint live ranges)

    k_setup<<<1024, 256, 0, stream>>>(W0, W1, W2, x, Wb0, Wb1, Wb2, hb);

    dim3 g0(32, 8);   // k_gemm0: 32 el-groups x 8 slices
    dim3 g(64, 8);    // k_contract: 64 el-groups x 8 slices

    // layer 0: I=128 Di=8 O=64 Do=16, IR=4 (2 x 64KB dbuf)
    k_gemm0<128,8,64,16,4><<<g0,512,0,stream>>>(Wb0, hb, psA);
    k_contract<128,8,64,16,4,1><<<g,512,0,stream>>>(Wb0, hb, vs, psA, psB);
    k_contract<128,8,64,16,4,2><<<g,512,0,stream>>>(Wb0, hb, vs, psB, psA);
    k_squash<64,16,2><<<256,256,0,stream>>>(psA, hb);      // h1 (overwrites x-pack)

    // layer 1: I=64 Di=16 O=32 Do=32, IR=2 (2 x 64KB dbuf)
    k_gemm0<64,16,32,32,2><<<g0,512,0,stream>>>(Wb1, hb, psA);
    k_contract<64,16,32,32,2,1><<<g,512,0,stream>>>(Wb1, hb, vs, psA, psB);
    k_contract<64,16,32,32,2,2><<<g,512,0,stream>>>(Wb1, hb, vs, psB, psA);
    k_squash<32,32,2><<<256,256,0,stream>>>(psA, hb);      // h2 (overwrites h1)

    // layer 2: I=32 Di=32 O=10 Do=64, IR=1 (2 x 40KB dbuf)
    k_gemm0<32,32,10,64,1><<<g0,512,0,stream>>>(Wb2, hb, psA);
    k_contract<32,32,10,64,1,1><<<g,512,0,stream>>>(Wb2, hb, vs, psA, psB);
    k_contract<32,32,10,64,1,2><<<g,512,0,stream>>>(Wb2, hb, vs, psB, psA);
    k_squash<10,64,3><<<256,256,0,stream>>>(psA, out);     // ||v2||
}